// Round 2
// baseline (209.042 us; speedup 1.0000x reference)
//
#include <hip/hip_runtime.h>

// Inverse SWT (db4, 3 levels), T=4096, circular.
// One block per row. res + detail live in LDS (float4, XOR-swizzled to kill
// the 64B-stride bank conflict). Each thread computes 16 contiguous outputs:
// the 8-tap window at dilation D spans 16+7D floats -> {11,8,6} float4 reads
// per array per level (vs 8 per 4 outputs in the gather formulation).

namespace {

constexpr int TT = 4096;
constexpr int T4 = TT / 4;   // 1024 float4 per row
constexpr int NT = 256;

// XOR swizzle on float4 index: lane stride of 4 float4 (64 B) maps all lanes
// of a 16-lane phase onto 8 banks (8-way conflict). f ^ ((f>>3)&7) spreads
// them across all 32 banks (b128-minimum 2 accesses/bank). Bijective, stays
// in [0, T4).
__device__ __forceinline__ int swz(int f) { return f ^ ((f >> 3) & 7); }

__constant__ const float LO[8] = {
    0.23037781330885523f,  0.7148465705525415f,   0.6308807679295904f,
    -0.02798376941698385f, -0.18703481171888114f, 0.030841381835986965f,
    0.032883011666982945f, -0.010597401784997278f};
__constant__ const float HI[8] = {
    -0.010597401784997278f, -0.032883011666982945f, 0.030841381835986965f,
    0.18703481171888114f,   -0.02798376941698385f,  -0.6308807679295904f,
    0.7148465705525415f,    -0.23037781330885523f};

template <int D>
__device__ __forceinline__ void compute_level(const float4* __restrict__ A,
                                              const float4* __restrict__ B,
                                              int t, float* __restrict__ a) {
  // Outputs n0..n0+15, n0 = 16t. Taps reach [n0-4D, n0+15+3D]:
  // window = 16+7D floats starting at s = n0-4D (float4-aligned for D=1,2,4).
  // res tap m for output j reads w[(7-m)*D + j].
  constexpr int W = (7 * D + 16 + 3) / 4;  // D=4 -> 11, D=2 -> 8, D=1 -> 6
  const int base = 4 * t - D;              // first float4 logical index
  float w[4 * W];

#pragma unroll
  for (int i = 0; i < W; ++i) {
    const float4 v = A[swz((base + i) & (T4 - 1))];
    w[4 * i + 0] = v.x; w[4 * i + 1] = v.y;
    w[4 * i + 2] = v.z; w[4 * i + 3] = v.w;
  }
#pragma unroll
  for (int j = 0; j < 16; ++j) a[j] = 0.f;
#pragma unroll
  for (int m = 0; m < 8; ++m) {
    const int o = (7 - m) * D;
#pragma unroll
    for (int j = 0; j < 16; ++j) a[j] += LO[m] * w[o + j];
  }

#pragma unroll
  for (int i = 0; i < W; ++i) {
    const float4 v = B[swz((base + i) & (T4 - 1))];
    w[4 * i + 0] = v.x; w[4 * i + 1] = v.y;
    w[4 * i + 2] = v.z; w[4 * i + 3] = v.w;
  }
#pragma unroll
  for (int m = 0; m < 8; ++m) {
    const int o = (7 - m) * D;
#pragma unroll
    for (int j = 0; j < 16; ++j) a[j] += HI[m] * w[o + j];
  }
#pragma unroll
  for (int j = 0; j < 16; ++j) a[j] *= 0.5f;
}

__device__ __forceinline__ void stage(float4* dst, const float4* r, int t) {
#pragma unroll
  for (int k = 0; k < 4; ++k) dst[swz(t + k * NT)] = r[k];
}

__device__ __forceinline__ void writeback(float4* A, const float* a, int t) {
#pragma unroll
  for (int j = 0; j < 4; ++j)
    A[swz(4 * t + j)] =
        make_float4(a[4 * j + 0], a[4 * j + 1], a[4 * j + 2], a[4 * j + 3]);
}

// __launch_bounds__(256,4): cap ~128 VGPR so the scheduler can't hoist both
// windows' loads at once; 4 blocks/CU (LDS 32 KiB/block allows 5).
__global__ __launch_bounds__(NT, 4) void iswt_kernel(
    const float* __restrict__ x, float* __restrict__ out) {
  __shared__ float4 A[T4];  // running reconstruction
  __shared__ float4 B[T4];  // current level's detail

  const int t = threadIdx.x;
  const int row = blockIdx.x;  // input rows 4r..4r+3 = cA3, cD3, cD2, cD1

  const float4* xr = reinterpret_cast<const float4*>(x) + (size_t)row * 4 * T4;

  float4 rA[4], rB[4];
#pragma unroll
  for (int k = 0; k < 4; ++k) rA[k] = xr[0 * T4 + t + k * NT];
#pragma unroll
  for (int k = 0; k < 4; ++k) rB[k] = xr[1 * T4 + t + k * NT];
  stage(A, rA, t);
  stage(B, rB, t);
  __syncthreads();

  float4 rH[4];
#pragma unroll
  for (int k = 0; k < 4; ++k) rH[k] = xr[2 * T4 + t + k * NT];  // prefetch cD2

  float a[16];
  compute_level<4>(A, B, t, a);
  __syncthreads();
  writeback(A, a, t);
  stage(B, rH, t);
  __syncthreads();

#pragma unroll
  for (int k = 0; k < 4; ++k) rH[k] = xr[3 * T4 + t + k * NT];  // prefetch cD1

  compute_level<2>(A, B, t, a);
  __syncthreads();
  writeback(A, a, t);
  stage(B, rH, t);
  __syncthreads();

  compute_level<1>(A, B, t, a);

  float4* o4 = reinterpret_cast<float4*>(out) + (size_t)row * T4;
#pragma unroll
  for (int j = 0; j < 4; ++j)
    o4[4 * t + j] =
        make_float4(a[4 * j + 0], a[4 * j + 1], a[4 * j + 2], a[4 * j + 3]);
}

}  // namespace

extern "C" void kernel_launch(void* const* d_in, const int* in_sizes, int n_in,
                              void* d_out, int out_size, void* d_ws, size_t ws_size,
                              hipStream_t stream) {
  const float* x = reinterpret_cast<const float*>(d_in[0]);
  float* out = reinterpret_cast<float*>(d_out);
  const int rows = out_size / TT;  // 2048
  iswt_kernel<<<rows, NT, 0, stream>>>(x, out);
}